// Round 1
// baseline (545.745 us; speedup 1.0000x reference)
//
#include <hip/hip_runtime.h>
#include <hip/hip_bf16.h>
#include <stdint.h>
#include <math.h>

#define B_ 2
#define S_ 2048
#define H_ 2048
#define NH_ 16
#define NKV_ 4
#define HD_ 128

typedef __bf16 bf16;
typedef __bf16 bf16x8 __attribute__((ext_vector_type(8)));
typedef __bf16 bf16x4 __attribute__((ext_vector_type(4)));
typedef float f32x4 __attribute__((ext_vector_type(4)));

__device__ __forceinline__ void async_copy16(const void* g, void* l) {
  __builtin_amdgcn_global_load_lds(
      (const __attribute__((address_space(1))) void*)(uintptr_t)g,
      (__attribute__((address_space(3))) void*)(uintptr_t)l,
      16, 0, 0);
}

__device__ __forceinline__ f32x4 mfma16(bf16x8 a, bf16x8 b, f32x4 c) {
  return __builtin_amdgcn_mfma_f32_16x16x32_bf16(a, b, c, 0, 0, 0);
}

// ---------------- prep kernels ----------------

__global__ void f32_to_bf16_k(const float* __restrict__ in, bf16* __restrict__ o, int n) {
  int i = (blockIdx.x * 256 + threadIdx.x) * 4;
  if (i >= n) return;
  float4 v = *(const float4*)(in + i);
  bf16x4 r;
  r[0] = (bf16)v.x; r[1] = (bf16)v.y; r[2] = (bf16)v.z; r[3] = (bf16)v.w;
  *(bf16x4*)(o + i) = r;
}

// W: K x N f32 row-major  ->  Wt: N x K bf16 row-major
__global__ void transpose_to_bf16_k(const float* __restrict__ W, bf16* __restrict__ Wt,
                                    int K, int N) {
  __shared__ float tile[32][33];
  int n0 = blockIdx.x * 32, k0 = blockIdx.y * 32;
  int tx = threadIdx.x, ty = threadIdx.y;
#pragma unroll
  for (int j = 0; j < 32; j += 8)
    tile[ty + j][tx] = W[(size_t)(k0 + ty + j) * N + n0 + tx];
  __syncthreads();
#pragma unroll
  for (int j = 0; j < 32; j += 8)
    Wt[(size_t)(n0 + ty + j) * K + k0 + tx] = (bf16)tile[tx][ty + j];
}

__global__ void rope_table_k(float2* __restrict__ tab) {
  int i = blockIdx.x * 256 + threadIdx.x;  // S_*64
  int p = i >> 6, d = i & 63;
  float invf = expf(-((float)(2 * d) / 128.0f) * 9.210340371976184f);  // 10000^(-2d/128)
  float fr = (float)p * invf;
  float sv, cv;
  sincosf(fr, &sv, &cv);
  tab[i] = make_float2(cv, sv);
}

// in-place RoPE on (rows=B*S, nheads, 128); pair (d, d+64); optional scale fold
__global__ void rope_apply_k(bf16* __restrict__ t, const int* __restrict__ pos_ids,
                             const float2* __restrict__ tab, int hshift, int hmask,
                             float scale) {
  int i = blockIdx.x * 256 + threadIdx.x;
  int d = i & 63;
  int tmp = i >> 6;
  int h = tmp & hmask;
  int row = tmp >> hshift;
  int pos = pos_ids[row];
  float2 cs = tab[pos * 64 + d];
  size_t base = (((size_t)row << hshift) + h) * HD_;
  float a = (float)t[base + d];
  float b = (float)t[base + d + 64];
  t[base + d]      = (bf16)((a * cs.x - b * cs.y) * scale);
  t[base + d + 64] = (bf16)((b * cs.x + a * cs.y) * scale);
}

// ---------------- GEMM: C(MxN) = A(MxK) * Bt(NxK)^T, bf16 in, f32 acc ----------------
// 128x128 tile, BK=64, 4 waves (2x2 of 64x64). LDS rows 128B (8 x 16B slots),
// XOR swizzle slot^(row&7); global_load_lds linear dest + pre-swizzled source (rule #21).

template <bool OUT_F32>
__global__ __launch_bounds__(256) void gemm_bt_k(const bf16* __restrict__ A,
                                                 const bf16* __restrict__ Bt0,
                                                 const bf16* __restrict__ Bt1,
                                                 void* __restrict__ C0, void* __restrict__ C1,
                                                 int M, int N, int K) {
  const bf16* __restrict__ Bt = (blockIdx.z == 0) ? Bt0 : Bt1;
  void* C = (blockIdx.z == 0) ? C0 : C1;
  __shared__ __align__(16) bf16 As[128 * 64];
  __shared__ __align__(16) bf16 Bs[128 * 64];
  const int tid = threadIdx.x;
  const int lane = tid & 63;
  const int w = tid >> 6;
  const int wm = w >> 1, wn = w & 1;
  const int g16 = lane >> 4, c16 = lane & 15;
  const int row0 = blockIdx.y * 128;
  const int col0 = blockIdx.x * 128;
  const int sr = lane >> 3;       // row within 8-row staging group
  const int st = lane & 7;        // stored 16B slot
  const int ss = st ^ sr;         // logical slot (source pre-swizzle)

  const f32x4 fz = {0.f, 0.f, 0.f, 0.f};
  f32x4 acc[4][4];
#pragma unroll
  for (int i = 0; i < 4; ++i)
#pragma unroll
    for (int j = 0; j < 4; ++j) acc[i][j] = fz;

  const int nkt = K >> 6;
  for (int kt = 0; kt < nkt; ++kt) {
    const int k0 = kt << 6;
    __syncthreads();  // previous compute done before overwrite
#pragma unroll
    for (int c = 0; c < 4; ++c) {
      int rbase = w * 32 + c * 8;
      async_copy16(A + (size_t)(row0 + rbase + sr) * K + k0 + ss * 8,
                   (char*)As + rbase * 128);
      async_copy16(Bt + (size_t)(col0 + rbase + sr) * K + k0 + ss * 8,
                   (char*)Bs + rbase * 128);
    }
    __syncthreads();  // staging visible (compiler drains vmcnt before barrier)
#pragma unroll
    for (int ks = 0; ks < 2; ++ks) {
      bf16x8 af[4], bfr[4];
#pragma unroll
      for (int t = 0; t < 4; ++t) {
        int ra = wm * 64 + t * 16 + c16;
        af[t] = *(const bf16x8*)((const char*)As + ra * 128 + (((ks * 4 + g16) ^ (ra & 7)) << 4));
        int rb = wn * 64 + t * 16 + c16;
        bfr[t] = *(const bf16x8*)((const char*)Bs + rb * 128 + (((ks * 4 + g16) ^ (rb & 7)) << 4));
      }
#pragma unroll
      for (int i = 0; i < 4; ++i)
#pragma unroll
        for (int j = 0; j < 4; ++j) acc[i][j] = mfma16(af[i], bfr[j], acc[i][j]);
    }
  }

  // C/D mapping: col = lane&15, row = (lane>>4)*4 + reg   [m89/m91]
#pragma unroll
  for (int i = 0; i < 4; ++i) {
    int gr0 = row0 + wm * 64 + i * 16 + g16 * 4;
#pragma unroll
    for (int j = 0; j < 4; ++j) {
      int gc = col0 + wn * 64 + j * 16 + c16;
#pragma unroll
      for (int r = 0; r < 4; ++r) {
        if constexpr (OUT_F32)
          ((float*)C)[(size_t)(gr0 + r) * N + gc] = acc[i][j][r];
        else
          ((bf16*)C)[(size_t)(gr0 + r) * N + gc] = (bf16)acc[i][j][r];
      }
    }
  }
}

// ---------------- flash attention (causal, GQA) ----------------
// QBLK=64, KVBLK=64, 4 waves: wave w owns q rows [w*16, w*16+16).
// Scale 1/sqrt(128) pre-folded into Q. grid = (S/64, B*NH).

__global__ __launch_bounds__(256) void attn_fwd_k(const bf16* __restrict__ Qg,
                                                  const bf16* __restrict__ Kg,
                                                  const bf16* __restrict__ Vg,
                                                  bf16* __restrict__ Og) {
  __shared__ __align__(16) bf16 Qs[64 * 128];   // rows 256B, 16 slots, swz slot^(r&7)
  __shared__ __align__(16) bf16 Ks[64 * 128];
  __shared__ __align__(16) bf16 VTs[128 * 64];  // V^T: rows=d (128B, 8 slots), cols=kv
  __shared__ __align__(16) bf16 Ps[64 * 64];    // P tile, rows 128B

  const int tid = threadIdx.x;
  const int lane = tid & 63;
  const int w = tid >> 6;
  const int g16 = lane >> 4;
  const int c16 = lane & 15;
  const int qb = blockIdx.x;
  const int bh = blockIdx.y;
  const int b = bh >> 4;    // NH=16
  const int h = bh & 15;
  const int hkv = h >> 2;   // GROUPS=4
  const int q0 = qb * 64;

  // stage Q once (pre-swizzled source, linear LDS dest)
#pragma unroll
  for (int c = 0; c < 4; ++c) {
    int r = w * 16 + c * 4 + g16;
    int s = c16 ^ (r & 7);
    async_copy16(Qg + ((size_t)(b * S_ + q0 + r) * NH_ + h) * HD_ + s * 8,
                 (char*)Qs + (w * 16 + c * 4) * 256);
  }

  float m_run[4] = {-INFINITY, -INFINITY, -INFINITY, -INFINITY};
  float l_run[4] = {0.f, 0.f, 0.f, 0.f};
  const f32x4 fz = {0.f, 0.f, 0.f, 0.f};
  f32x4 acc_o[8];
#pragma unroll
  for (int dt = 0; dt < 8; ++dt) acc_o[dt] = fz;

  for (int kvb = 0; kvb <= qb; ++kvb) {
    const int kv0 = kvb * 64;
    // Phase 1: async K stage + V loads to regs
#pragma unroll
    for (int c = 0; c < 4; ++c) {
      int r = w * 16 + c * 4 + g16;
      int s = c16 ^ (r & 7);
      async_copy16(Kg + ((size_t)(b * S_ + kv0 + r) * NKV_ + hkv) * HD_ + s * 8,
                   (char*)Ks + (w * 16 + c * 4) * 256);
    }
    bf16x8 vreg[4];
#pragma unroll
    for (int c = 0; c < 4; ++c) {
      int sid = c * 256 + tid;
      int kv = sid >> 4, d8 = sid & 15;
      vreg[c] = *(const bf16x8*)(Vg + ((size_t)(b * S_ + kv0 + kv) * NKV_ + hkv) * HD_ + d8 * 8);
    }
    __syncthreads();  // B1: previous PV done -> VTs free
    // Phase 3: transpose V into LDS
#pragma unroll
    for (int c = 0; c < 4; ++c) {
      int sid = c * 256 + tid;
      int kv = sid >> 4, d8 = sid & 15;
#pragma unroll
      for (int j = 0; j < 8; ++j) {
        int d = d8 * 8 + j;
        *(bf16*)((char*)VTs + d * 128 + (((kv >> 3) ^ (d & 7)) << 4) + (kv & 7) * 2) = vreg[c][j];
      }
    }
    __syncthreads();  // B2: K + VT staged

    // QK^T: A=Q rows, B=K rows (K-contiguous both sides)
    f32x4 sc[4];
#pragma unroll
    for (int nt = 0; nt < 4; ++nt) sc[nt] = fz;
#pragma unroll
    for (int ks = 0; ks < 4; ++ks) {
      int rq = w * 16 + c16;
      bf16x8 aq = *(const bf16x8*)((const char*)Qs + rq * 256 + (((ks * 4 + g16) ^ (rq & 7)) << 4));
#pragma unroll
      for (int nt = 0; nt < 4; ++nt) {
        int rk = nt * 16 + c16;
        bf16x8 bk = *(const bf16x8*)((const char*)Ks + rk * 256 + (((ks * 4 + g16) ^ (rk & 7)) << 4));
        sc[nt] = mfma16(aq, bk, sc[nt]);
      }
    }

    // causal mask on diagonal block (D layout: row=(l>>4)*4+r, col=l&15)
    if (kvb == qb) {
#pragma unroll
      for (int nt = 0; nt < 4; ++nt) {
        int col = nt * 16 + c16;
#pragma unroll
        for (int r = 0; r < 4; ++r) {
          int rowl = w * 16 + g16 * 4 + r;
          if (col > rowl) sc[nt][r] = -INFINITY;
        }
      }
    }

    // online softmax: row lives across lanes [g16*16, g16*16+16)
#pragma unroll
    for (int r = 0; r < 4; ++r) {
      float v = fmaxf(fmaxf(sc[0][r], sc[1][r]), fmaxf(sc[2][r], sc[3][r]));
      v = fmaxf(v, __shfl_xor(v, 1));
      v = fmaxf(v, __shfl_xor(v, 2));
      v = fmaxf(v, __shfl_xor(v, 4));
      v = fmaxf(v, __shfl_xor(v, 8));
      float mn = fmaxf(m_run[r], v);
      float corr = __expf(m_run[r] - mn);
      m_run[r] = mn;
      float sum = 0.f;
#pragma unroll
      for (int nt = 0; nt < 4; ++nt) {
        float pv = __expf(sc[nt][r] - mn);
        sc[nt][r] = pv;
        sum += pv;
      }
      sum += __shfl_xor(sum, 1);
      sum += __shfl_xor(sum, 2);
      sum += __shfl_xor(sum, 4);
      sum += __shfl_xor(sum, 8);
      l_run[r] = l_run[r] * corr + sum;
#pragma unroll
      for (int dt = 0; dt < 8; ++dt) acc_o[dt][r] *= corr;
    }

    // write P (bf16) to LDS in A-fragment-consumable row-major + swizzle
#pragma unroll
    for (int nt = 0; nt < 4; ++nt) {
      int col = nt * 16 + c16;
      int slotc = col >> 3;
      int wb = (col & 7) * 2;
#pragma unroll
      for (int r = 0; r < 4; ++r) {
        int rowl = w * 16 + g16 * 4 + r;
        *(bf16*)((char*)Ps + rowl * 128 + ((slotc ^ (rowl & 7)) << 4) + wb) = (bf16)sc[nt][r];
      }
    }
    __syncthreads();  // B3: P visible

    // PV: A=P rows (k=kv), B=V^T rows (col=d, k=kv contiguous)
#pragma unroll
    for (int ks = 0; ks < 2; ++ks) {
      int rp = w * 16 + c16;
      bf16x8 ap = *(const bf16x8*)((const char*)Ps + rp * 128 + (((ks * 4 + g16) ^ (rp & 7)) << 4));
#pragma unroll
      for (int dt = 0; dt < 8; ++dt) {
        int rv = dt * 16 + c16;
        bf16x8 bv = *(const bf16x8*)((const char*)VTs + rv * 128 + (((ks * 4 + g16) ^ (rv & 7)) << 4));
        acc_o[dt] = mfma16(ap, bv, acc_o[dt]);
      }
    }
  }

  // epilogue: O = acc / l
#pragma unroll
  for (int dt = 0; dt < 8; ++dt) {
#pragma unroll
    for (int r = 0; r < 4; ++r) {
      int rowl = w * 16 + g16 * 4 + r;
      float v = acc_o[dt][r] / l_run[r];
      Og[((size_t)(b * S_ + q0 + rowl) * NH_ + h) * HD_ + dt * 16 + c16] = (bf16)v;
    }
  }
}

// ---------------- launcher ----------------

extern "C" void kernel_launch(void* const* d_in, const int* in_sizes, int n_in,
                              void* d_out, int out_size, void* d_ws, size_t ws_size,
                              hipStream_t stream) {
  const float* x  = (const float*)d_in[0];
  // d_in[1] attention_mask: fixed causal -> computed analytically
  const int* pos  = (const int*)d_in[2];
  const float* Wq = (const float*)d_in[3];
  const float* Wk = (const float*)d_in[4];
  const float* Wv = (const float*)d_in[5];
  const float* Wo = (const float*)d_in[6];

  char* ws = (char*)d_ws;
  size_t off = 0;
  auto alloc = [&](size_t bytes) -> char* {
    char* p = ws + off;
    off += (bytes + 255) & ~(size_t)255;
    return p;
  };
  const size_t rows = (size_t)B_ * S_;            // 4096
  bf16* xb   = (bf16*)alloc(rows * H_ * 2);       // x bf16
  bf16* bq   = (bf16*)alloc(rows * (NH_ * HD_) * 2);
  bf16* batt = (bf16*)alloc(rows * (NH_ * HD_) * 2);
  bf16* WqT  = (bf16*)alloc((size_t)H_ * (NH_ * HD_) * 2);
  bf16* WoT  = (bf16*)alloc((size_t)H_ * H_ * 2);
  bf16* bk   = (bf16*)alloc(rows * (NKV_ * HD_) * 2);
  bf16* bv   = (bf16*)alloc(rows * (NKV_ * HD_) * 2);
  bf16* WkT  = (bf16*)alloc((size_t)H_ * (NKV_ * HD_) * 2);
  bf16* WvT  = (bf16*)alloc((size_t)H_ * (NKV_ * HD_) * 2);
  float2* tab = (float2*)alloc((size_t)S_ * 64 * sizeof(float2));

  // prep
  f32_to_bf16_k<<<(rows * H_) / (256 * 4), 256, 0, stream>>>(x, xb, rows * H_);
  transpose_to_bf16_k<<<dim3(H_ / 32, H_ / 32), dim3(32, 8), 0, stream>>>(Wq, WqT, H_, NH_ * HD_);
  transpose_to_bf16_k<<<dim3((NKV_ * HD_) / 32, H_ / 32), dim3(32, 8), 0, stream>>>(Wk, WkT, H_, NKV_ * HD_);
  transpose_to_bf16_k<<<dim3((NKV_ * HD_) / 32, H_ / 32), dim3(32, 8), 0, stream>>>(Wv, WvT, H_, NKV_ * HD_);
  transpose_to_bf16_k<<<dim3(H_ / 32, H_ / 32), dim3(32, 8), 0, stream>>>(Wo, WoT, H_, H_);
  rope_table_k<<<(S_ * 64) / 256, 256, 0, stream>>>(tab);

  // projections
  gemm_bt_k<false><<<dim3(16, 32, 1), 256, 0, stream>>>(xb, WqT, WqT, bq, bq, 4096, 2048, 2048);
  gemm_bt_k<false><<<dim3(4, 32, 2), 256, 0, stream>>>(xb, WkT, WvT, bk, bv, 4096, 512, 2048);

  // RoPE (scale 1/sqrt(128) folded into Q)
  rope_apply_k<<<(4096 * NH_ * 64) / 256, 256, 0, stream>>>(bq, pos, tab, 4, 15, 0.08838834764831845f);
  rope_apply_k<<<(4096 * NKV_ * 64) / 256, 256, 0, stream>>>(bk, pos, tab, 2, 3, 1.0f);

  // attention
  attn_fwd_k<<<dim3(S_ / 64, B_ * NH_), 256, 0, stream>>>(bq, bk, bv, batt);

  // output projection (f32 out)
  gemm_bt_k<true><<<dim3(16, 32, 1), 256, 0, stream>>>(batt, WoT, WoT, d_out, d_out, 4096, 2048, 2048);
}

// Round 2
// 241.198 us; speedup vs baseline: 2.2626x; 2.2626x over previous
//
#include <hip/hip_runtime.h>
#include <hip/hip_bf16.h>
#include <stdint.h>
#include <math.h>

#define B_ 2
#define S_ 2048
#define H_ 2048
#define NH_ 16
#define NKV_ 4
#define HD_ 128

typedef __bf16 bf16;
typedef __bf16 bf16x8 __attribute__((ext_vector_type(8)));
typedef __bf16 bf16x4 __attribute__((ext_vector_type(4)));
typedef float f32x4 __attribute__((ext_vector_type(4)));

__device__ __forceinline__ void async_copy16(const void* g, void* l) {
  __builtin_amdgcn_global_load_lds(
      (const __attribute__((address_space(1))) void*)(uintptr_t)g,
      (__attribute__((address_space(3))) void*)(uintptr_t)l,
      16, 0, 0);
}

__device__ __forceinline__ f32x4 mfma16(bf16x8 a, bf16x8 b, f32x4 c) {
  return __builtin_amdgcn_mfma_f32_16x16x32_bf16(a, b, c, 0, 0, 0);
}

// ---------------- prep kernels ----------------

__global__ void f32_to_bf16_k(const float* __restrict__ in, bf16* __restrict__ o, int n) {
  int i = (blockIdx.x * 256 + threadIdx.x) * 4;
  if (i >= n) return;
  float4 v = *(const float4*)(in + i);
  bf16x4 r;
  r[0] = (bf16)v.x; r[1] = (bf16)v.y; r[2] = (bf16)v.z; r[3] = (bf16)v.w;
  *(bf16x4*)(o + i) = r;
}

// W: K x N f32 row-major  ->  Wt: N x K bf16 row-major
__global__ void transpose_to_bf16_k(const float* __restrict__ W, bf16* __restrict__ Wt,
                                    int K, int N) {
  __shared__ float tile[32][33];
  int n0 = blockIdx.x * 32, k0 = blockIdx.y * 32;
  int tx = threadIdx.x, ty = threadIdx.y;
#pragma unroll
  for (int j = 0; j < 32; j += 8)
    tile[ty + j][tx] = W[(size_t)(k0 + ty + j) * N + n0 + tx];
  __syncthreads();
#pragma unroll
  for (int j = 0; j < 32; j += 8)
    Wt[(size_t)(n0 + ty + j) * K + k0 + tx] = (bf16)tile[tx][ty + j];
}

__global__ void rope_table_k(float2* __restrict__ tab) {
  int i = blockIdx.x * 256 + threadIdx.x;  // S_*64
  int p = i >> 6, d = i & 63;
  float invf = expf(-((float)(2 * d) / 128.0f) * 9.210340371976184f);  // 10000^(-2d/128)
  float fr = (float)p * invf;
  float sv, cv;
  sincosf(fr, &sv, &cv);
  tab[i] = make_float2(cv, sv);
}

// in-place RoPE on (rows=B*S, nheads, 128); pair (d, d+64); optional scale fold
__global__ void rope_apply_k(bf16* __restrict__ t, const int* __restrict__ pos_ids,
                             const float2* __restrict__ tab, int hshift, int hmask,
                             float scale) {
  int i = blockIdx.x * 256 + threadIdx.x;
  int d = i & 63;
  int tmp = i >> 6;
  int h = tmp & hmask;
  int row = tmp >> hshift;
  int pos = pos_ids[row];
  float2 cs = tab[pos * 64 + d];
  size_t base = (((size_t)row << hshift) + h) * HD_;
  float a = (float)t[base + d];
  float b = (float)t[base + d + 64];
  t[base + d]      = (bf16)((a * cs.x - b * cs.y) * scale);
  t[base + d + 64] = (bf16)((b * cs.x + a * cs.y) * scale);
}

// ---------------- GEMM: C(MxN) = A(MxK) * Bt(NxK)^T, bf16 in, f32 acc ----------------
// 128x128 tile, BK=64, 4 waves (2x2 of 64x64). VT_Z1: blockIdx.z==1 writes output
// transposed as [b][hkv][d][S] (V^T for attention), packed 8B stores.

template <bool OUT_F32, bool VT_Z1>
__global__ __launch_bounds__(256) void gemm_bt_k(const bf16* __restrict__ A,
                                                 const bf16* __restrict__ Bt0,
                                                 const bf16* __restrict__ Bt1,
                                                 void* __restrict__ C0, void* __restrict__ C1,
                                                 int M, int N, int K) {
  const bf16* __restrict__ Bt = (blockIdx.z == 0) ? Bt0 : Bt1;
  void* C = (blockIdx.z == 0) ? C0 : C1;
  __shared__ __align__(16) bf16 As[128 * 64];
  __shared__ __align__(16) bf16 Bs[128 * 64];
  const int tid = threadIdx.x;
  const int lane = tid & 63;
  const int w = tid >> 6;
  const int wm = w >> 1, wn = w & 1;
  const int g16 = lane >> 4, c16 = lane & 15;
  const int row0 = blockIdx.y * 128;
  const int col0 = blockIdx.x * 128;
  const int sr = lane >> 3;
  const int st = lane & 7;
  const int ss = st ^ sr;

  const f32x4 fz = {0.f, 0.f, 0.f, 0.f};
  f32x4 acc[4][4];
#pragma unroll
  for (int i = 0; i < 4; ++i)
#pragma unroll
    for (int j = 0; j < 4; ++j) acc[i][j] = fz;

  const int nkt = K >> 6;
  for (int kt = 0; kt < nkt; ++kt) {
    const int k0 = kt << 6;
    __syncthreads();
#pragma unroll
    for (int c = 0; c < 4; ++c) {
      int rbase = w * 32 + c * 8;
      async_copy16(A + (size_t)(row0 + rbase + sr) * K + k0 + ss * 8,
                   (char*)As + rbase * 128);
      async_copy16(Bt + (size_t)(col0 + rbase + sr) * K + k0 + ss * 8,
                   (char*)Bs + rbase * 128);
    }
    __syncthreads();
#pragma unroll
    for (int ks = 0; ks < 2; ++ks) {
      bf16x8 af[4], bfr[4];
#pragma unroll
      for (int t = 0; t < 4; ++t) {
        int ra = wm * 64 + t * 16 + c16;
        af[t] = *(const bf16x8*)((const char*)As + ra * 128 + (((ks * 4 + g16) ^ (ra & 7)) << 4));
        int rb = wn * 64 + t * 16 + c16;
        bfr[t] = *(const bf16x8*)((const char*)Bs + rb * 128 + (((ks * 4 + g16) ^ (rb & 7)) << 4));
      }
#pragma unroll
      for (int i = 0; i < 4; ++i)
#pragma unroll
        for (int j = 0; j < 4; ++j) acc[i][j] = mfma16(af[i], bfr[j], acc[i][j]);
    }
  }

  // C/D mapping: col = lane&15, row = (lane>>4)*4 + reg
  const bool vt = VT_Z1 && (blockIdx.z == 1);
#pragma unroll
  for (int i = 0; i < 4; ++i) {
    int gr0 = row0 + wm * 64 + i * 16 + g16 * 4;
#pragma unroll
    for (int j = 0; j < 4; ++j) {
      int gc = col0 + wn * 64 + j * 16 + c16;
      if (vt) {
        // V^T: [b][hkv][d][S], 4 consecutive s per lane -> 8B packed store
        size_t va = ((size_t)((gr0 >> 11) * NKV_ + (gc >> 7)) * HD_ + (gc & 127)) * S_ + (gr0 & 2047);
        bf16x4 pk;
#pragma unroll
        for (int r = 0; r < 4; ++r) pk[r] = (bf16)acc[i][j][r];
        *(bf16x4*)((bf16*)C + va) = pk;
      } else {
#pragma unroll
        for (int r = 0; r < 4; ++r) {
          if constexpr (OUT_F32)
            ((float*)C)[(size_t)(gr0 + r) * N + gc] = acc[i][j][r];
          else
            ((bf16*)C)[(size_t)(gr0 + r) * N + gc] = (bf16)acc[i][j][r];
        }
      }
    }
  }
}

// ---------------- flash attention v2 (causal, GQA) ----------------
// QBLK=128 (4 waves x 32 q-rows), KVBLK=64, swapped QK^T (mfma(K,Q)) with
// permuted K rows so P lands in-lane in PV B-fragment order. Q in registers,
// K/V^T double-buffered LDS via global_load_lds. exp2-domain softmax
// (log2e/sqrt(HD) pre-folded into Q). grid = 512 blocks, heavy-qb-first remap.

__global__ __launch_bounds__(256, 2) void attn_fwd_k(const bf16* __restrict__ Qg,
                                                     const bf16* __restrict__ Kg,
                                                     const bf16* __restrict__ VTg,
                                                     bf16* __restrict__ Og) {
  __shared__ __align__(16) bf16 Ks[2][64 * 128];   // rows 256B (16 slots), swz slot^(row&7)
  __shared__ __align__(16) bf16 Vt[2][128 * 64];   // rows 128B (8 slots),  swz slot^(row&7)

  const int tid = threadIdx.x;
  const int lane = tid & 63;
  const int w = tid >> 6;
  const int g16 = lane >> 4;
  const int c16 = lane & 15;

  // block remap: first 256 blocks get qb 15..8, next 256 get qb 0..7 (pairs sum ~const)
  int bid = blockIdx.x;
  int rr_ = bid >> 5, bh = bid & 31;
  int qb = (rr_ < 8) ? (15 - rr_) : (rr_ - 8);
  const int b = bh >> 4;
  const int h = bh & 15;
  const int hkv = h >> 2;
  const int q0 = qb * 128;
  const int qw = q0 + w * 32;

  // Q fragments in registers: qf[nq][ksq] = Q[qw+nq*16+c16][(ksq*4+g16)*8 ..+8]
  bf16x8 qf[2][4];
#pragma unroll
  for (int nq = 0; nq < 2; ++nq)
#pragma unroll
    for (int ksq = 0; ksq < 4; ++ksq)
      qf[nq][ksq] = *(const bf16x8*)(Qg + ((size_t)(b * S_ + qw + nq * 16 + c16) * NH_ + h) * HD_ + (ksq * 4 + g16) * 8);

  float m_run[2] = {-1e30f, -1e30f};
  float l_run[2] = {0.f, 0.f};
  const f32x4 fz = {0.f, 0.f, 0.f, 0.f};
  f32x4 acc[2][8];
#pragma unroll
  for (int nq = 0; nq < 2; ++nq)
#pragma unroll
    for (int dt = 0; dt < 8; ++dt) acc[nq][dt] = fz;

  const size_t kbase = ((size_t)b * S_ * NKV_ + hkv) * HD_;             // + (kv)*NKV_*HD_ ...
  const size_t vbase = ((size_t)(b * NKV_ + hkv)) * HD_ * S_;           // + row*S_ + kv

  auto stage = [&](int buf, int kv0) {
#pragma unroll
    for (int rd = 0; rd < 4; ++rd) {
      int Lb = rd * 256 + w * 64;
      int row = (Lb + lane) >> 4;                 // 4 rows per wave-round
      int ssl = (lane & 15) ^ (row & 7);
      async_copy16(Kg + kbase + (size_t)(kv0 + row) * (NKV_ * HD_) + ssl * 8,
                   (char*)&Ks[buf][0] + Lb * 16);
    }
#pragma unroll
    for (int rd = 0; rd < 4; ++rd) {
      int Lb = rd * 256 + w * 64;
      int row = (Lb + lane) >> 3;                 // 8 rows per wave-round
      int ssl = (lane & 7) ^ (row & 7);
      async_copy16(VTg + vbase + (size_t)row * S_ + kv0 + ssl * 8,
                   (char*)&Vt[buf][0] + Lb * 16);
    }
  };

  const int ntiles = 2 * qb + 2;
  stage(0, 0);
  int cur = 0;

  for (int t = 0; t < ntiles; ++t) {
    __syncthreads();  // drains stage(t) vmcnt; separates compute(t-1) from stage(t+1)
    if (t + 1 < ntiles) stage(cur ^ 1, (t + 1) * 64);
    const int kv0 = t * 64;

    if (kv0 <= qw + 31) {  // wave has at least one unmasked element in this tile
      const bf16* KsC = &Ks[cur][0];
      const bf16* VtC = &Vt[cur][0];

      // ---- swapped QK^T: D[m=kv(perm)][n=q] ----
      f32x4 sc[2][4];
#pragma unroll
      for (int nq = 0; nq < 2; ++nq)
#pragma unroll
        for (int mt = 0; mt < 4; ++mt) sc[nq][mt] = fz;

#pragma unroll
      for (int ksq = 0; ksq < 4; ++ksq) {
        bf16x8 kf[4];
#pragma unroll
        for (int mt = 0; mt < 4; ++mt) {
          int gp = c16 >> 2, rp = c16 & 3;
          int blk = 8 * (mt >> 1) + 2 * gp + ((mt & 1) ^ (gp & 1));
          int row = blk * 4 + rp;
          kf[mt] = *(const bf16x8*)((const char*)KsC + row * 256 + (((ksq * 4 + g16) ^ (row & 7)) << 4));
        }
#pragma unroll
        for (int nq = 0; nq < 2; ++nq)
#pragma unroll
          for (int mt = 0; mt < 4; ++mt)
            sc[nq][mt] = mfma16(kf[mt], qf[nq][ksq], sc[nq][mt]);
      }

      // ---- causal mask (exact per element; kv of sc[nq][mt][r] = blk(mt,g16)*4+r) ----
      if (kv0 + 63 > qw) {
#pragma unroll
        for (int nq = 0; nq < 2; ++nq) {
          int qa = qw + nq * 16 + c16;
#pragma unroll
          for (int mt = 0; mt < 4; ++mt) {
            int blk = 8 * (mt >> 1) + 2 * g16 + ((mt & 1) ^ (g16 & 1));
#pragma unroll
            for (int r = 0; r < 4; ++r) {
              int ka = kv0 + blk * 4 + r;
              if (ka > qa) sc[nq][mt][r] = -1e30f;
            }
          }
        }
      }

      // ---- online softmax (base-2 domain) ----
#pragma unroll
      for (int nq = 0; nq < 2; ++nq) {
        float mx = sc[nq][0][0];
#pragma unroll
        for (int mt = 0; mt < 4; ++mt)
#pragma unroll
          for (int r = 0; r < 4; ++r) mx = fmaxf(mx, sc[nq][mt][r]);
        mx = fmaxf(mx, __shfl_xor(mx, 16));
        mx = fmaxf(mx, __shfl_xor(mx, 32));
        float mn = fmaxf(m_run[nq], mx);
        float corr = exp2f(m_run[nq] - mn);
        m_run[nq] = mn;
        float sum = 0.f;
#pragma unroll
        for (int mt = 0; mt < 4; ++mt)
#pragma unroll
          for (int r = 0; r < 4; ++r) {
            float p = exp2f(sc[nq][mt][r] - mn);
            sc[nq][mt][r] = p;
            sum += p;
          }
        sum += __shfl_xor(sum, 16);
        sum += __shfl_xor(sum, 32);
        l_run[nq] = l_run[nq] * corr + sum;
#pragma unroll
        for (int dt = 0; dt < 8; ++dt) acc[nq][dt] *= corr;
      }

      // ---- P -> bf16 fragments, fully in-lane (permutation made it so) ----
      bf16x8 pa[2][2];
#pragma unroll
      for (int nq = 0; nq < 2; ++nq)
#pragma unroll
        for (int ks = 0; ks < 2; ++ks) {
          f32x4 sA = (g16 & 1) ? sc[nq][2 * ks + 1] : sc[nq][2 * ks];
          f32x4 sB = (g16 & 1) ? sc[nq][2 * ks] : sc[nq][2 * ks + 1];
          bf16x8 tf;
          tf[0] = (bf16)sA[0]; tf[1] = (bf16)sA[1]; tf[2] = (bf16)sA[2]; tf[3] = (bf16)sA[3];
          tf[4] = (bf16)sB[0]; tf[5] = (bf16)sB[1]; tf[6] = (bf16)sB[2]; tf[7] = (bf16)sB[3];
          pa[nq][ks] = tf;
        }

      // ---- PV: D[m=d][n=q] += V^T-frag x P-frag ----
#pragma unroll
      for (int ks = 0; ks < 2; ++ks)
#pragma unroll
        for (int dt = 0; dt < 8; ++dt) {
          int rv = dt * 16 + c16;
          bf16x8 vf = *(const bf16x8*)((const char*)VtC + rv * 128 + (((ks * 4 + g16) ^ (rv & 7)) << 4));
          acc[0][dt] = mfma16(vf, pa[0][ks], acc[0][dt]);
          acc[1][dt] = mfma16(vf, pa[1][ks], acc[1][dt]);
        }
    }
    cur ^= 1;
  }

  // ---- epilogue: O[q][d] = acc^T / l, packed 8B stores ----
#pragma unroll
  for (int nq = 0; nq < 2; ++nq) {
    float inv = 1.0f / l_run[nq];
    size_t base = ((size_t)(b * S_ + qw + nq * 16 + c16) * NH_ + h) * HD_ + g16 * 4;
#pragma unroll
    for (int dt = 0; dt < 8; ++dt) {
      bf16x4 ov;
#pragma unroll
      for (int r = 0; r < 4; ++r) ov[r] = (bf16)(acc[nq][dt][r] * inv);
      *(bf16x4*)(Og + base + dt * 16) = ov;
    }
  }
}

// ---------------- launcher ----------------

extern "C" void kernel_launch(void* const* d_in, const int* in_sizes, int n_in,
                              void* d_out, int out_size, void* d_ws, size_t ws_size,
                              hipStream_t stream) {
  const float* x  = (const float*)d_in[0];
  // d_in[1] attention_mask: fixed causal -> computed analytically
  const int* pos  = (const int*)d_in[2];
  const float* Wq = (const float*)d_in[3];
  const float* Wk = (const float*)d_in[4];
  const float* Wv = (const float*)d_in[5];
  const float* Wo = (const float*)d_in[6];

  char* ws = (char*)d_ws;
  size_t off = 0;
  auto alloc = [&](size_t bytes) -> char* {
    char* p = ws + off;
    off += (bytes + 255) & ~(size_t)255;
    return p;
  };
  const size_t rows = (size_t)B_ * S_;            // 4096
  bf16* xb   = (bf16*)alloc(rows * H_ * 2);
  bf16* bq   = (bf16*)alloc(rows * (NH_ * HD_) * 2);
  bf16* batt = (bf16*)alloc(rows * (NH_ * HD_) * 2);
  bf16* WqT  = (bf16*)alloc((size_t)H_ * (NH_ * HD_) * 2);
  bf16* WoT  = (bf16*)alloc((size_t)H_ * H_ * 2);
  bf16* bk   = (bf16*)alloc(rows * (NKV_ * HD_) * 2);
  bf16* VT   = (bf16*)alloc(rows * (NKV_ * HD_) * 2);   // [b][hkv][d][S]
  bf16* WkT  = (bf16*)alloc((size_t)H_ * (NKV_ * HD_) * 2);
  bf16* WvT  = (bf16*)alloc((size_t)H_ * (NKV_ * HD_) * 2);
  float2* tab = (float2*)alloc((size_t)S_ * 64 * sizeof(float2));

  // prep
  f32_to_bf16_k<<<(rows * H_) / (256 * 4), 256, 0, stream>>>(x, xb, rows * H_);
  transpose_to_bf16_k<<<dim3(H_ / 32, H_ / 32), dim3(32, 8), 0, stream>>>(Wq, WqT, H_, NH_ * HD_);
  transpose_to_bf16_k<<<dim3((NKV_ * HD_) / 32, H_ / 32), dim3(32, 8), 0, stream>>>(Wk, WkT, H_, NKV_ * HD_);
  transpose_to_bf16_k<<<dim3((NKV_ * HD_) / 32, H_ / 32), dim3(32, 8), 0, stream>>>(Wv, WvT, H_, NKV_ * HD_);
  transpose_to_bf16_k<<<dim3(H_ / 32, H_ / 32), dim3(32, 8), 0, stream>>>(Wo, WoT, H_, H_);
  rope_table_k<<<(S_ * 64) / 256, 256, 0, stream>>>(tab);

  // projections (z=1 of the KV gemm writes V transposed)
  gemm_bt_k<false, false><<<dim3(16, 32, 1), 256, 0, stream>>>(xb, WqT, WqT, bq, bq, 4096, 2048, 2048);
  gemm_bt_k<false, true><<<dim3(4, 32, 2), 256, 0, stream>>>(xb, WkT, WvT, bk, VT, 4096, 512, 2048);

  // RoPE: Q gets 1/sqrt(HD) * log2(e) folded in (exp2-domain softmax)
  rope_apply_k<<<(4096 * NH_ * 64) / 256, 256, 0, stream>>>(bq, pos, tab, 4, 15, 0.12753102f);
  rope_apply_k<<<(4096 * NKV_ * 64) / 256, 256, 0, stream>>>(bk, pos, tab, 2, 3, 1.0f);

  // attention
  attn_fwd_k<<<dim3(512), 256, 0, stream>>>(bq, bk, VT, batt);

  // output projection (f32 out)
  gemm_bt_k<true, false><<<dim3(16, 32, 1), 256, 0, stream>>>(batt, WoT, WoT, d_out, d_out, 4096, 2048, 2048);
}

// Round 3
// 226.892 us; speedup vs baseline: 2.4053x; 1.0631x over previous
//
#include <hip/hip_runtime.h>
#include <hip/hip_bf16.h>
#include <stdint.h>
#include <math.h>

#define B_ 2
#define S_ 2048
#define H_ 2048
#define NH_ 16
#define NKV_ 4
#define HD_ 128

typedef __bf16 bf16;
typedef __bf16 bf16x8 __attribute__((ext_vector_type(8)));
typedef __bf16 bf16x4 __attribute__((ext_vector_type(4)));
typedef float f32x4 __attribute__((ext_vector_type(4)));

__device__ __forceinline__ void async_copy16(const void* g, void* l) {
  __builtin_amdgcn_global_load_lds(
      (const __attribute__((address_space(1))) void*)(uintptr_t)g,
      (__attribute__((address_space(3))) void*)(uintptr_t)l,
      16, 0, 0);
}

__device__ __forceinline__ f32x4 mfma16(bf16x8 a, bf16x8 b, f32x4 c) {
  return __builtin_amdgcn_mfma_f32_16x16x32_bf16(a, b, c, 0, 0, 0);
}

// ---------------- prep kernels ----------------

__global__ void f32_to_bf16_k(const float* __restrict__ in, bf16* __restrict__ o, int n) {
  int i = (blockIdx.x * 256 + threadIdx.x) * 4;
  if (i >= n) return;
  float4 v = *(const float4*)(in + i);
  bf16x4 r;
  r[0] = (bf16)v.x; r[1] = (bf16)v.y; r[2] = (bf16)v.z; r[3] = (bf16)v.w;
  *(bf16x4*)(o + i) = r;
}

// W: K x N f32 row-major  ->  Wt: N x K bf16 row-major
__global__ void transpose_to_bf16_k(const float* __restrict__ W, bf16* __restrict__ Wt,
                                    int K, int N) {
  __shared__ float tile[32][33];
  int n0 = blockIdx.x * 32, k0 = blockIdx.y * 32;
  int tx = threadIdx.x, ty = threadIdx.y;
#pragma unroll
  for (int j = 0; j < 32; j += 8)
    tile[ty + j][tx] = W[(size_t)(k0 + ty + j) * N + n0 + tx];
  __syncthreads();
#pragma unroll
  for (int j = 0; j < 32; j += 8)
    Wt[(size_t)(n0 + ty + j) * K + k0 + tx] = (bf16)tile[tx][ty + j];
}

__global__ void rope_table_k(float2* __restrict__ tab) {
  int i = blockIdx.x * 256 + threadIdx.x;  // S_*64
  int p = i >> 6, d = i & 63;
  float invf = expf(-((float)(2 * d) / 128.0f) * 9.210340371976184f);  // 10000^(-2d/128)
  float fr = (float)p * invf;
  float sv, cv;
  sincosf(fr, &sv, &cv);
  tab[i] = make_float2(cv, sv);
}

// in-place RoPE on (rows=B*S, nheads, 128); pair (d, d+64); optional scale fold
__global__ void rope_apply_k(bf16* __restrict__ t, const int* __restrict__ pos_ids,
                             const float2* __restrict__ tab, int hshift, int hmask,
                             float scale) {
  int i = blockIdx.x * 256 + threadIdx.x;
  int d = i & 63;
  int tmp = i >> 6;
  int h = tmp & hmask;
  int row = tmp >> hshift;
  int pos = pos_ids[row];
  float2 cs = tab[pos * 64 + d];
  size_t base = (((size_t)row << hshift) + h) * HD_;
  float a = (float)t[base + d];
  float b = (float)t[base + d + 64];
  t[base + d]      = (bf16)((a * cs.x - b * cs.y) * scale);
  t[base + d + 64] = (bf16)((b * cs.x + a * cs.y) * scale);
}

// ---------------- 8-phase GEMM: C(MxN) = A(MxK) * Bt(NxK)^T ----------------
// BM=128, BN=256, BK=64; 8 waves (2M x 4N), 64x64 per wave. 3-stage LDS pipeline
// (144 KiB dynamic), counted vmcnt(6) (6 staging loads per K-tile, 1 tile ahead).
// Per K-tile: 4 phases of {ds_read | stage-issue | barrier | lgkm0 | 8 MFMA | barrier}.

template <bool OUT_F32>
__global__ __launch_bounds__(512) void gemm8_k(const bf16* __restrict__ A,
                                               const bf16* __restrict__ Bt,
                                               void* __restrict__ Cv,
                                               int M, int N, int K) {
  extern __shared__ __align__(16) char smem[];
  const int tid = threadIdx.x;
  const int lane = tid & 63;
  const int w = tid >> 6;
  const int wm = w >> 2;          // 0..1
  const int wn = w & 3;           // 0..3
  const int g16 = lane >> 4, c16 = lane & 15;
  const int row0 = blockIdx.y * 128;
  const int col0 = blockIdx.x * 256;
  const int srow = tid >> 3;      // staging row within 64-row round
  const int sslot = tid & 7;
  const int ldsw = w * 1024;      // wave-uniform LDS dest piece (HW adds lane*16)

  auto stageA = [&](int s, int kt, int r) {
    int row = r * 64 + srow;
    int ss = sslot ^ (row & 7);
    async_copy16(A + (size_t)(row0 + row) * K + (kt << 6) + ss * 8,
                 smem + s * 49152 + r * 8192 + ldsw);
  };
  auto stageB = [&](int s, int kt, int r) {
    int row = r * 64 + srow;
    int ss = sslot ^ (row & 7);
    async_copy16(Bt + (size_t)(col0 + row) * K + (kt << 6) + ss * 8,
                 smem + s * 49152 + 16384 + r * 8192 + ldsw);
  };

  int offA[2][4], offB[2][4];
#pragma unroll
  for (int ks = 0; ks < 2; ++ks) {
#pragma unroll
    for (int i = 0; i < 4; ++i) {
      int ra = wm * 64 + i * 16 + c16;
      offA[ks][i] = ra * 128 + (((ks * 4 + g16) ^ (ra & 7)) << 4);
      int rb = wn * 64 + i * 16 + c16;
      offB[ks][i] = rb * 128 + (((ks * 4 + g16) ^ (rb & 7)) << 4);
    }
  }

  const f32x4 fz = {0.f, 0.f, 0.f, 0.f};
  f32x4 acc[4][4];
#pragma unroll
  for (int i = 0; i < 4; ++i)
#pragma unroll
    for (int j = 0; j < 4; ++j) acc[i][j] = fz;

  const int nkt = K >> 6;
  // prologue: stage tiles 0 and 1
#pragma unroll
  for (int r = 0; r < 2; ++r) stageA(0, 0, r);
#pragma unroll
  for (int r = 0; r < 4; ++r) stageB(0, 0, r);
#pragma unroll
  for (int r = 0; r < 2; ++r) stageA(1, 1, r);
#pragma unroll
  for (int r = 0; r < 4; ++r) stageB(1, 1, r);
  asm volatile("s_waitcnt vmcnt(6)" ::: "memory");
  __builtin_amdgcn_s_barrier();

  int ct = 0, pt = 2;
  for (int t = 0; t < nkt; ++t) {
    const char* Ab = smem + ct * 49152;
    const char* Bb = Ab + 16384;
    const bool pf = (t + 2 < nkt);
    const int kpf = t + 2;
    bf16x8 a0[4], a1[4], bx[2];

    // ---- phase 1: A ks0 + B j01 ks0 ----
#pragma unroll
    for (int i = 0; i < 4; ++i) a0[i] = *(const bf16x8*)(Ab + offA[0][i]);
    bx[0] = *(const bf16x8*)(Bb + offB[0][0]);
    bx[1] = *(const bf16x8*)(Bb + offB[0][1]);
    if (pf) { stageA(pt, kpf, 0); stageA(pt, kpf, 1); }
    asm volatile("" ::: "memory");
    __builtin_amdgcn_s_barrier();
    asm volatile("s_waitcnt lgkmcnt(0)" ::: "memory");
    __builtin_amdgcn_sched_barrier(0);
    __builtin_amdgcn_s_setprio(1);
#pragma unroll
    for (int i = 0; i < 4; ++i) {
      acc[i][0] = mfma16(a0[i], bx[0], acc[i][0]);
      acc[i][1] = mfma16(a0[i], bx[1], acc[i][1]);
    }
    __builtin_amdgcn_s_setprio(0);
    __builtin_amdgcn_sched_barrier(0);
    asm volatile("" ::: "memory");
    __builtin_amdgcn_s_barrier();

    // ---- phase 2: B j23 ks0 ----
    bx[0] = *(const bf16x8*)(Bb + offB[0][2]);
    bx[1] = *(const bf16x8*)(Bb + offB[0][3]);
    if (pf) { stageB(pt, kpf, 0); stageB(pt, kpf, 1); }
    asm volatile("" ::: "memory");
    __builtin_amdgcn_s_barrier();
    asm volatile("s_waitcnt lgkmcnt(0)" ::: "memory");
    __builtin_amdgcn_sched_barrier(0);
    __builtin_amdgcn_s_setprio(1);
#pragma unroll
    for (int i = 0; i < 4; ++i) {
      acc[i][2] = mfma16(a0[i], bx[0], acc[i][2]);
      acc[i][3] = mfma16(a0[i], bx[1], acc[i][3]);
    }
    __builtin_amdgcn_s_setprio(0);
    __builtin_amdgcn_sched_barrier(0);
    asm volatile("" ::: "memory");
    __builtin_amdgcn_s_barrier();

    // ---- phase 3: A ks1 + B j01 ks1 ----
#pragma unroll
    for (int i = 0; i < 4; ++i) a1[i] = *(const bf16x8*)(Ab + offA[1][i]);
    bx[0] = *(const bf16x8*)(Bb + offB[1][0]);
    bx[1] = *(const bf16x8*)(Bb + offB[1][1]);
    if (pf) { stageB(pt, kpf, 2); stageB(pt, kpf, 3); }
    asm volatile("" ::: "memory");
    __builtin_amdgcn_s_barrier();
    asm volatile("s_waitcnt lgkmcnt(0)" ::: "memory");
    __builtin_amdgcn_sched_barrier(0);
    __builtin_amdgcn_s_setprio(1);
#pragma unroll
    for (int i = 0; i < 4; ++i) {
      acc[i][0] = mfma16(a1[i], bx[0], acc[i][0]);
      acc[i][1] = mfma16(a1[i], bx[1], acc[i][1]);
    }
    __builtin_amdgcn_s_setprio(0);
    __builtin_amdgcn_sched_barrier(0);
    asm volatile("" ::: "memory");
    __builtin_amdgcn_s_barrier();

    // ---- phase 4: B j23 ks1; counted vmcnt for next tile ----
    bx[0] = *(const bf16x8*)(Bb + offB[1][2]);
    bx[1] = *(const bf16x8*)(Bb + offB[1][3]);
    if (pf) asm volatile("s_waitcnt vmcnt(6)" ::: "memory");
    else    asm volatile("s_waitcnt vmcnt(0)" ::: "memory");
    __builtin_amdgcn_s_barrier();
    asm volatile("s_waitcnt lgkmcnt(0)" ::: "memory");
    __builtin_amdgcn_sched_barrier(0);
    __builtin_amdgcn_s_setprio(1);
#pragma unroll
    for (int i = 0; i < 4; ++i) {
      acc[i][2] = mfma16(a1[i], bx[0], acc[i][2]);
      acc[i][3] = mfma16(a1[i], bx[1], acc[i][3]);
    }
    __builtin_amdgcn_s_setprio(0);
    __builtin_amdgcn_sched_barrier(0);
    asm volatile("" ::: "memory");
    __builtin_amdgcn_s_barrier();

    ct = (ct == 2) ? 0 : ct + 1;
    pt = (pt == 2) ? 0 : pt + 1;
  }

  // C/D mapping: col = lane&15, row = (lane>>4)*4 + reg
#pragma unroll
  for (int i = 0; i < 4; ++i) {
    int gr0 = row0 + wm * 64 + i * 16 + g16 * 4;
#pragma unroll
    for (int j = 0; j < 4; ++j) {
      int gc = col0 + wn * 64 + j * 16 + c16;
#pragma unroll
      for (int r = 0; r < 4; ++r) {
        if constexpr (OUT_F32)
          ((float*)Cv)[(size_t)(gr0 + r) * N + gc] = acc[i][j][r];
        else
          ((bf16*)Cv)[(size_t)(gr0 + r) * N + gc] = (bf16)acc[i][j][r];
      }
    }
  }
}

// ---------------- legacy 128^2 GEMM (KV projection + fallback) ----------------

template <bool OUT_F32, bool VT_Z1>
__global__ __launch_bounds__(256) void gemm_bt_k(const bf16* __restrict__ A,
                                                 const bf16* __restrict__ Bt0,
                                                 const bf16* __restrict__ Bt1,
                                                 void* __restrict__ C0, void* __restrict__ C1,
                                                 int M, int N, int K) {
  const bf16* __restrict__ Bt = (blockIdx.z == 0) ? Bt0 : Bt1;
  void* C = (blockIdx.z == 0) ? C0 : C1;
  __shared__ __align__(16) bf16 As[128 * 64];
  __shared__ __align__(16) bf16 Bs[128 * 64];
  const int tid = threadIdx.x;
  const int lane = tid & 63;
  const int w = tid >> 6;
  const int wm = w >> 1, wn = w & 1;
  const int g16 = lane >> 4, c16 = lane & 15;
  const int row0 = blockIdx.y * 128;
  const int col0 = blockIdx.x * 128;
  const int sr = lane >> 3;
  const int st = lane & 7;
  const int ss = st ^ sr;

  const f32x4 fz = {0.f, 0.f, 0.f, 0.f};
  f32x4 acc[4][4];
#pragma unroll
  for (int i = 0; i < 4; ++i)
#pragma unroll
    for (int j = 0; j < 4; ++j) acc[i][j] = fz;

  const int nkt = K >> 6;
  for (int kt = 0; kt < nkt; ++kt) {
    const int k0 = kt << 6;
    __syncthreads();
#pragma unroll
    for (int c = 0; c < 4; ++c) {
      int rbase = w * 32 + c * 8;
      async_copy16(A + (size_t)(row0 + rbase + sr) * K + k0 + ss * 8,
                   (char*)As + rbase * 128);
      async_copy16(Bt + (size_t)(col0 + rbase + sr) * K + k0 + ss * 8,
                   (char*)Bs + rbase * 128);
    }
    __syncthreads();
#pragma unroll
    for (int ks = 0; ks < 2; ++ks) {
      bf16x8 af[4], bfr[4];
#pragma unroll
      for (int t = 0; t < 4; ++t) {
        int ra = wm * 64 + t * 16 + c16;
        af[t] = *(const bf16x8*)((const char*)As + ra * 128 + (((ks * 4 + g16) ^ (ra & 7)) << 4));
        int rb = wn * 64 + t * 16 + c16;
        bfr[t] = *(const bf16x8*)((const char*)Bs + rb * 128 + (((ks * 4 + g16) ^ (rb & 7)) << 4));
      }
#pragma unroll
      for (int i = 0; i < 4; ++i)
#pragma unroll
        for (int j = 0; j < 4; ++j) acc[i][j] = mfma16(af[i], bfr[j], acc[i][j]);
    }
  }

  const bool vt = VT_Z1 && (blockIdx.z == 1);
#pragma unroll
  for (int i = 0; i < 4; ++i) {
    int gr0 = row0 + wm * 64 + i * 16 + g16 * 4;
#pragma unroll
    for (int j = 0; j < 4; ++j) {
      int gc = col0 + wn * 64 + j * 16 + c16;
      if (vt) {
        size_t va = ((size_t)((gr0 >> 11) * NKV_ + (gc >> 7)) * HD_ + (gc & 127)) * S_ + (gr0 & 2047);
        bf16x4 pk;
#pragma unroll
        for (int r = 0; r < 4; ++r) pk[r] = (bf16)acc[i][j][r];
        *(bf16x4*)((bf16*)C + va) = pk;
      } else {
#pragma unroll
        for (int r = 0; r < 4; ++r) {
          if constexpr (OUT_F32)
            ((float*)C)[(size_t)(gr0 + r) * N + gc] = acc[i][j][r];
          else
            ((bf16*)C)[(size_t)(gr0 + r) * N + gc] = (bf16)acc[i][j][r];
        }
      }
    }
  }
}

// ---------------- flash attention (causal, GQA) ----------------
// QBLK=128 (4 waves x 32 q-rows), KVBLK=64, swapped QK^T with permuted K rows
// so P is fully in-lane for PV. exp2-domain softmax + T13 defer-max.

__global__ __launch_bounds__(256, 2) void attn_fwd_k(const bf16* __restrict__ Qg,
                                                     const bf16* __restrict__ Kg,
                                                     const bf16* __restrict__ VTg,
                                                     bf16* __restrict__ Og) {
  __shared__ __align__(16) bf16 Ks[2][64 * 128];   // rows 256B (16 slots), swz slot^(row&7)
  __shared__ __align__(16) bf16 Vt[2][128 * 64];   // rows 128B (8 slots),  swz slot^(row&7)

  const int tid = threadIdx.x;
  const int lane = tid & 63;
  const int w = tid >> 6;
  const int g16 = lane >> 4;
  const int c16 = lane & 15;

  int bid = blockIdx.x;
  int rr_ = bid >> 5, bh = bid & 31;
  int qb = (rr_ < 8) ? (15 - rr_) : (rr_ - 8);
  const int b = bh >> 4;
  const int h = bh & 15;
  const int hkv = h >> 2;
  const int q0 = qb * 128;
  const int qw = q0 + w * 32;

  bf16x8 qf[2][4];
#pragma unroll
  for (int nq = 0; nq < 2; ++nq)
#pragma unroll
    for (int ksq = 0; ksq < 4; ++ksq)
      qf[nq][ksq] = *(const bf16x8*)(Qg + ((size_t)(b * S_ + qw + nq * 16 + c16) * NH_ + h) * HD_ + (ksq * 4 + g16) * 8);

  float m_run[2] = {-1e30f, -1e30f};
  float l_run[2] = {0.f, 0.f};
  const f32x4 fz = {0.f, 0.f, 0.f, 0.f};
  f32x4 acc[2][8];
#pragma unroll
  for (int nq = 0; nq < 2; ++nq)
#pragma unroll
    for (int dt = 0; dt < 8; ++dt) acc[nq][dt] = fz;

  const size_t kbase = ((size_t)b * S_ * NKV_ + hkv) * HD_;
  const size_t vbase = ((size_t)(b * NKV_ + hkv)) * HD_ * S_;

  auto stage = [&](int buf, int kv0) {
#pragma unroll
    for (int rd = 0; rd < 4; ++rd) {
      int Lb = rd * 256 + w * 64;
      int row = (Lb + lane) >> 4;
      int ssl = (lane & 15) ^ (row & 7);
      async_copy16(Kg + kbase + (size_t)(kv0 + row) * (NKV_ * HD_) + ssl * 8,
                   (char*)&Ks[buf][0] + Lb * 16);
    }
#pragma unroll
    for (int rd = 0; rd < 4; ++rd) {
      int Lb = rd * 256 + w * 64;
      int row = (Lb + lane) >> 3;
      int ssl = (lane & 7) ^ (row & 7);
      async_copy16(VTg + vbase + (size_t)row * S_ + kv0 + ssl * 8,
                   (char*)&Vt[buf][0] + Lb * 16);
    }
  };

  const int ntiles = 2 * qb + 2;
  stage(0, 0);
  int cur = 0;

  for (int t = 0; t < ntiles; ++t) {
    __syncthreads();
    if (t + 1 < ntiles) stage(cur ^ 1, (t + 1) * 64);
    const int kv0 = t * 64;

    if (kv0 <= qw + 31) {
      const bf16* KsC = &Ks[cur][0];
      const bf16* VtC = &Vt[cur][0];

      f32x4 sc[2][4];
#pragma unroll
      for (int nq = 0; nq < 2; ++nq)
#pragma unroll
        for (int mt = 0; mt < 4; ++mt) sc[nq][mt] = fz;

#pragma unroll
      for (int ksq = 0; ksq < 4; ++ksq) {
        bf16x8 kf[4];
#pragma unroll
        for (int mt = 0; mt < 4; ++mt) {
          int gp = c16 >> 2, rp = c16 & 3;
          int blk = 8 * (mt >> 1) + 2 * gp + ((mt & 1) ^ (gp & 1));
          int row = blk * 4 + rp;
          kf[mt] = *(const bf16x8*)((const char*)KsC + row * 256 + (((ksq * 4 + g16) ^ (row & 7)) << 4));
        }
#pragma unroll
        for (int nq = 0; nq < 2; ++nq)
#pragma unroll
          for (int mt = 0; mt < 4; ++mt)
            sc[nq][mt] = mfma16(kf[mt], qf[nq][ksq], sc[nq][mt]);
      }

      if (kv0 + 63 > qw) {
#pragma unroll
        for (int nq = 0; nq < 2; ++nq) {
          int qa = qw + nq * 16 + c16;
#pragma unroll
          for (int mt = 0; mt < 4; ++mt) {
            int blk = 8 * (mt >> 1) + 2 * g16 + ((mt & 1) ^ (g16 & 1));
#pragma unroll
            for (int r = 0; r < 4; ++r) {
              int ka = kv0 + blk * 4 + r;
              if (ka > qa) sc[nq][mt][r] = -1e30f;
            }
          }
        }
      }

      // ---- online softmax (base-2) with T13 defer-max ----
      float mx[2];
#pragma unroll
      for (int nq = 0; nq < 2; ++nq) {
        float v = sc[nq][0][0];
#pragma unroll
        for (int mt = 0; mt < 4; ++mt)
#pragma unroll
          for (int r = 0; r < 4; ++r) v = fmaxf(v, sc[nq][mt][r]);
        v = fmaxf(v, __shfl_xor(v, 16));
        v = fmaxf(v, __shfl_xor(v, 32));
        mx[nq] = v;
      }
      if (__any((mx[0] > m_run[0] + 8.f) || (mx[1] > m_run[1] + 8.f))) {
#pragma unroll
        for (int nq = 0; nq < 2; ++nq) {
          float mn = fmaxf(m_run[nq], mx[nq]);
          float corr = exp2f(m_run[nq] - mn);
          m_run[nq] = mn;
          l_run[nq] *= corr;
#pragma unroll
          for (int dt = 0; dt < 8; ++dt) acc[nq][dt] *= corr;
        }
      }
#pragma unroll
      for (int nq = 0; nq < 2; ++nq) {
        float sum = 0.f;
#pragma unroll
        for (int mt = 0; mt < 4; ++mt)
#pragma unroll
          for (int r = 0; r < 4; ++r) {
            float p = exp2f(sc[nq][mt][r] - m_run[nq]);
            sc[nq][mt][r] = p;
            sum += p;
          }
        sum += __shfl_xor(sum, 16);
        sum += __shfl_xor(sum, 32);
        l_run[nq] += sum;
      }

      // ---- P -> bf16 fragments, in-lane ----
      bf16x8 pa[2][2];
#pragma unroll
      for (int nq = 0; nq < 2; ++nq)
#pragma unroll
        for (int ks = 0; ks < 2; ++ks) {
          f32x4 sA = (g16 & 1) ? sc[nq][2 * ks + 1] : sc[nq][2 * ks];
          f32x4 sB = (g16 & 1) ? sc[nq][2 * ks] : sc[nq][2 * ks + 1];
          bf16x8 tf;
          tf[0] = (bf16)sA[0]; tf[1] = (bf16)sA[1]; tf[2] = (bf16)sA[2]; tf[3] = (bf16)sA[3];
          tf[4] = (bf16)sB[0]; tf[5] = (bf16)sB[1]; tf[6] = (bf16)sB[2]; tf[7] = (bf16)sB[3];
          pa[nq][ks] = tf;
        }

      // ---- PV ----
#pragma unroll
      for (int ks = 0; ks < 2; ++ks)
#pragma unroll
        for (int dt = 0; dt < 8; ++dt) {
          int rv = dt * 16 + c16;
          bf16x8 vf = *(const bf16x8*)((const char*)VtC + rv * 128 + (((ks * 4 + g16) ^ (rv & 7)) << 4));
          acc[0][dt] = mfma16(vf, pa[0][ks], acc[0][dt]);
          acc[1][dt] = mfma16(vf, pa[1][ks], acc[1][dt]);
        }
    }
    cur ^= 1;
  }

#pragma unroll
  for (int nq = 0; nq < 2; ++nq) {
    float inv = 1.0f / l_run[nq];
    size_t base = ((size_t)(b * S_ + qw + nq * 16 + c16) * NH_ + h) * HD_ + g16 * 4;
#pragma unroll
    for (int dt = 0; dt < 8; ++dt) {
      bf16x4 ov;
#pragma unroll
      for (int r = 0; r < 4; ++r) ov[r] = (bf16)(acc[nq][dt][r] * inv);
      *(bf16x4*)(Og + base + dt * 16) = ov;
    }
  }
}

// ---------------- launcher ----------------

extern "C" void kernel_launch(void* const* d_in, const int* in_sizes, int n_in,
                              void* d_out, int out_size, void* d_ws, size_t ws_size,
                              hipStream_t stream) {
  const float* x  = (const float*)d_in[0];
  const int* pos  = (const int*)d_in[2];
  const float* Wq = (const float*)d_in[3];
  const float* Wk = (const float*)d_in[4];
  const float* Wv = (const float*)d_in[5];
  const float* Wo = (const float*)d_in[6];

  char* ws = (char*)d_ws;
  size_t off = 0;
  auto alloc = [&](size_t bytes) -> char* {
    char* p = ws + off;
    off += (bytes + 255) & ~(size_t)255;
    return p;
  };
  const size_t rows = (size_t)B_ * S_;
  bf16* xb   = (bf16*)alloc(rows * H_ * 2);
  bf16* bq   = (bf16*)alloc(rows * (NH_ * HD_) * 2);
  bf16* batt = (bf16*)alloc(rows * (NH_ * HD_) * 2);
  bf16* WqT  = (bf16*)alloc((size_t)H_ * (NH_ * HD_) * 2);
  bf16* WoT  = (bf16*)alloc((size_t)H_ * H_ * 2);
  bf16* bk   = (bf16*)alloc(rows * (NKV_ * HD_) * 2);
  bf16* VT   = (bf16*)alloc(rows * (NKV_ * HD_) * 2);   // [b][hkv][d][S]
  bf16* WkT  = (bf16*)alloc((size_t)H_ * (NKV_ * HD_) * 2);
  bf16* WvT  = (bf16*)alloc((size_t)H_ * (NKV_ * HD_) * 2);
  float2* tab = (float2*)alloc((size_t)S_ * 64 * sizeof(float2));

  // enable 144 KiB dynamic LDS for the 8-phase GEMM (fallback to legacy if refused)
  auto* fq = gemm8_k<false>;
  auto* fo = gemm8_k<true>;
  const int dynlds = 3 * 49152;
  bool big =
      (hipFuncSetAttribute((const void*)fq, hipFuncAttributeMaxDynamicSharedMemorySize, dynlds) == hipSuccess) &&
      (hipFuncSetAttribute((const void*)fo, hipFuncAttributeMaxDynamicSharedMemorySize, dynlds) == hipSuccess);

  // prep
  f32_to_bf16_k<<<(rows * H_) / (256 * 4), 256, 0, stream>>>(x, xb, rows * H_);
  transpose_to_bf16_k<<<dim3(H_ / 32, H_ / 32), dim3(32, 8), 0, stream>>>(Wq, WqT, H_, NH_ * HD_);
  transpose_to_bf16_k<<<dim3((NKV_ * HD_) / 32, H_ / 32), dim3(32, 8), 0, stream>>>(Wk, WkT, H_, NKV_ * HD_);
  transpose_to_bf16_k<<<dim3((NKV_ * HD_) / 32, H_ / 32), dim3(32, 8), 0, stream>>>(Wv, WvT, H_, NKV_ * HD_);
  transpose_to_bf16_k<<<dim3(H_ / 32, H_ / 32), dim3(32, 8), 0, stream>>>(Wo, WoT, H_, H_);
  rope_table_k<<<(S_ * 64) / 256, 256, 0, stream>>>(tab);

  // Q projection
  if (big)
    gemm8_k<false><<<dim3(8, 32), 512, dynlds, stream>>>(xb, WqT, bq, 4096, 2048, 2048);
  else
    gemm_bt_k<false, false><<<dim3(16, 32, 1), 256, 0, stream>>>(xb, WqT, WqT, bq, bq, 4096, 2048, 2048);

  // KV projection (z=1 writes V transposed)
  gemm_bt_k<false, true><<<dim3(4, 32, 2), 256, 0, stream>>>(xb, WkT, WvT, bk, VT, 4096, 512, 2048);

  // RoPE: Q gets 1/sqrt(HD) * log2(e) folded in (exp2-domain softmax)
  rope_apply_k<<<(4096 * NH_ * 64) / 256, 256, 0, stream>>>(bq, pos, tab, 4, 15, 0.12753102f);
  rope_apply_k<<<(4096 * NKV_ * 64) / 256, 256, 0, stream>>>(bk, pos, tab, 2, 3, 1.0f);

  // attention
  attn_fwd_k<<<dim3(512), 256, 0, stream>>>(bq, bk, VT, batt);

  // output projection (f32 out)
  if (big)
    gemm8_k<true><<<dim3(8, 32), 512, dynlds, stream>>>(batt, WoT, d_out, 4096, 2048, 2048);
  else
    gemm_bt_k<true, false><<<dim3(16, 32, 1), 256, 0, stream>>>(batt, WoT, WoT, d_out, d_out, 4096, 2048, 2048);
}